// Round 10
// baseline (1716.115 us; speedup 1.0000x reference)
//
#include <hip/hip_runtime.h>
#include <hip/hip_fp16.h>
#include <cstdint>

#define HC 168    // H*C (logical)
#define CC 42     // C per head
#define NH 4      // heads
#define PH 44     // padded channels per head
#define SLW 22    // slice width in halves; 8 slices cover 176
#define AP 192    // actv row pitch (halves), zero-padded K for KCN=6
#define A0P 64    // act0 row pitch (halves), KCN=2
#define NEG 0.2f
#define NPASS 8   // XCD-locality passes for hist/scatter

typedef _Float16 f16;
typedef __attribute__((ext_vector_type(8))) _Float16 f16x8;
typedef __attribute__((ext_vector_type(4))) float f32x4;

__device__ __forceinline__ float lrelu(float v) { return fmaxf(v, NEG * v); }
__device__ __forceinline__ float eluf(float v)  { return v > 0.f ? v : __expf(v) - 1.f; }

// ---- wconv as device fn: one item = one f16x8 of the fragment table ----
__device__ __forceinline__ void wconv_item(
    const float* __restrict__ W, f16* __restrict__ Wf, int i,
    int KCN, int kpad, int Fink, int cpad, int Ncols, int wstride) {
  int lane = i & 63;
  int t = i >> 6;
  int kc = t % KCN;
  int ct = t / KCN;
  int cl = ct * 16 + (lane & 15);
  int corig; bool cok;
  if (cpad) { int h = cl / PH, c = cl % PH; cok = (c < CC && h < NH); corig = h * CC + c; }
  else      { cok = (cl < Ncols); corig = cl; }
  f16 vals[8];
#pragma unroll
  for (int j = 0; j < 8; ++j) {
    int kp = kc * 32 + (lane >> 4) * 8 + j;
    int korig; bool kok;
    if (kpad) { int h = kp / PH, c = kp % PH; kok = (c < CC && h < NH && kp < 4 * PH); korig = h * CC + c; }
    else      { kok = (kp < Fink); korig = kp; }
    vals[j] = (kok && cok) ? (f16)W[korig * wstride + corig] : (f16)0.f;
  }
  *(f16x8*)(Wf + (size_t)i * 8) = *(f16x8*)vals;
}

// ---- prep: weight tables + padded alpha tables + zero cursor/sums/actv-pads ----
__global__ void prep_kernel(
    const float* __restrict__ lin0_w,
    const float* __restrict__ W1, const float* __restrict__ W2, const float* __restrict__ W3,
    const float* __restrict__ as1, const float* __restrict__ ad1,
    const float* __restrict__ as2, const float* __restrict__ ad2,
    const float* __restrict__ as3, const float* __restrict__ ad3,
    f16* __restrict__ Wf0, f16* __restrict__ Wf1, f16* __restrict__ Wf2, f16* __restrict__ Wf3,
    float* __restrict__ aPad,   // [3][2][176]
    int* __restrict__ cursor, float* __restrict__ sums, f16* __restrict__ actv,
    int N, int G) {
  const int W0N = 4 * 2 * 64, W1N = 11 * 2 * 64, W2N = 11 * 6 * 64;
  int i = blockIdx.x * 256 + threadIdx.x;
  if (i < N) { cursor[i] = 0; return; }
  i -= N;
  if (i < G * HC) { sums[i] = 0.f; return; }
  i -= G * HC;
  if (i < N * 4) {   // zero actv K-pad halves [176,192): 4 x uint2 per row
    int n = i >> 2, j = i & 3;
    *(uint2*)(actv + (size_t)n * AP + 176 + j * 4) = make_uint2(0u, 0u);
    return;
  }
  i -= N * 4;
  if (i < 3 * 2 * 176) {
    int l = i / 352, rem = i % 352, which = rem / 176, col = rem % 176;
    const float* tabs[6] = {as1, ad1, as2, ad2, as3, ad3};
    const float* tab = tabs[l * 2 + which];
    int h = col / PH, c = col % PH;
    aPad[i] = (c < CC) ? tab[h * CC + c] : 0.f;
    return;
  }
  i -= 3 * 2 * 176;
  if (i < W0N) { wconv_item(lin0_w, Wf0, i, 2, 0, CC, 0, CC, CC); return; }
  i -= W0N;
  if (i < W1N) { wconv_item(W1, Wf1, i, 2, 0, CC, 1, HC, HC); return; }
  i -= W1N;
  if (i < W2N) { wconv_item(W2, Wf2, i, 6, 1, HC, 1, HC, HC); return; }
  i -= W2N;
  if (i < W2N) { wconv_item(W3, Wf3, i, 6, 1, HC, 1, HC, HC); return; }
}

// ---- lin0 MFMA: act0[N,64] = elu(f16(x) @ Wf0 + b) ----
__global__ __launch_bounds__(256) void mfma_gemm0_kernel(
    const float* __restrict__ X, const f16* __restrict__ Wf,
    const float* __restrict__ bias, f16* __restrict__ Out, int N) {
  const int lane = threadIdx.x & 63;
  const int wid = (blockIdx.x * 256 + threadIdx.x) >> 6;
  const int row0 = wid * 16;
  if (row0 >= N) return;
  const int r = lane & 15, g = lane >> 4;
  f16x8 a[2];
  const float* xp = X + (int64_t)(row0 + r) * CC;
#pragma unroll
  for (int kc = 0; kc < 2; ++kc) {
#pragma unroll
    for (int j = 0; j < 8; ++j) {
      int k = kc * 32 + g * 8 + j;
      a[kc][j] = (k < CC) ? (f16)xp[k] : (f16)0.f;
    }
  }
  f16* op = Out + (int64_t)row0 * A0P;
#pragma unroll
  for (int ct = 0; ct < 4; ++ct) {
    f32x4 acc = {0.f, 0.f, 0.f, 0.f};
#pragma unroll
    for (int kc = 0; kc < 2; ++kc) {
      f16x8 b = *(const f16x8*)(Wf + (((size_t)ct * 2 + kc) * 64 + lane) * 8);
      acc = __builtin_amdgcn_mfma_f32_16x16x32_f16(a[kc], b, acc, 0, 0, 0);
    }
    const int col = ct * 16 + r;
    float bv = (col < CC) ? bias[col] : 0.f;
#pragma unroll
    for (int v = 0; v < 4; ++v) {
      f16 o = (col < CC) ? (f16)eluf(acc[v] + bv) : (f16)0.f;
      op[(int64_t)(g * 4 + v) * A0P + col] = o;
    }
  }
}

// ---- layer MFMA + fused alpha; writes SLICED gather table hs[8][N][22] ----
template<int KCN>
__global__ __launch_bounds__(256) void mfma_gemmL_kernel(
    const f16* __restrict__ A, const f16* __restrict__ Wf,
    const float* __restrict__ asP, const float* __restrict__ adP,
    f16* __restrict__ hs, float4* __restrict__ as4, float4* __restrict__ ad4,
    int N) {
  const int lane = threadIdx.x & 63;
  const int wid = (blockIdx.x * 256 + threadIdx.x) >> 6;
  const int row0 = wid * 16;
  if (row0 >= N) return;
  const int r = lane & 15, g = lane >> 4;
  f16x8 a[KCN];
  const f16* ap = A + (int64_t)(row0 + r) * (KCN * 32) + g * 8;
#pragma unroll
  for (int kc = 0; kc < KCN; ++kc) a[kc] = *(const f16x8*)(ap + kc * 32);
  float psA[4][4], psD[4][4];
#pragma unroll
  for (int h = 0; h < 4; ++h)
#pragma unroll
    for (int v = 0; v < 4; ++v) { psA[h][v] = 0.f; psD[h][v] = 0.f; }

#pragma unroll
  for (int ct = 0; ct < 11; ++ct) {
    f32x4 acc = {0.f, 0.f, 0.f, 0.f};
#pragma unroll
    for (int kc = 0; kc < KCN; ++kc) {
      f16x8 b = *(const f16x8*)(Wf + (((size_t)ct * KCN + kc) * 64 + lane) * 8);
      acc = __builtin_amdgcn_mfma_f32_16x16x32_f16(a[kc], b, acc, 0, 0, 0);
    }
    const int col = ct * 16 + r;       // 0..175; pads produce exact 0
    const int s = col / SLW;           // slice
    const int pos = col - s * SLW;
    const float aS = asP[col], aD = adP[col];
    const int hlo = (ct * 16) / PH;
    const bool hi = (col >= (hlo + 1) * PH);
#pragma unroll
    for (int v = 0; v < 4; ++v) {
      f16 hq = (f16)acc[v];
      hs[((size_t)s * N + (row0 + g * 4 + v)) * SLW + pos] = hq;
      float hf = (float)hq;
      float tA = hf * aS, tD = hf * aD;
      psA[hlo][v] += hi ? 0.f : tA;
      psD[hlo][v] += hi ? 0.f : tD;
      if (hlo < 3) {
        psA[hlo + 1][v] += hi ? tA : 0.f;
        psD[hlo + 1][v] += hi ? tD : 0.f;
      }
    }
  }
#pragma unroll
  for (int h = 0; h < 4; ++h)
#pragma unroll
    for (int v = 0; v < 4; ++v) {
      float aa = psA[h][v], dd = psD[h][v];
#pragma unroll
      for (int m = 1; m < 16; m <<= 1) {
        aa += __shfl_xor(aa, m, 64);
        dd += __shfl_xor(dd, m, 64);
      }
      psA[h][v] = aa; psD[h][v] = dd;
    }
  if (r < 4) {
    int row = row0 + g * 4 + r;
    as4[row] = make_float4(psA[0][r], psA[1][r], psA[2][r], psA[3][r]);
  } else if (r < 8) {
    int rr = r - 4;
    int row = row0 + g * 4 + rr;
    ad4[row] = make_float4(psD[0][rr], psD[1][rr], psD[2][rr], psD[3][rr]);
  }
}

// ---- wden: per layer, fp16 edge weights wE[4][E] (sorted order) + fp32 den[N][4] ----
__global__ __launch_bounds__(256) void wden_kernel(
    const int* __restrict__ row_ptr, const int* __restrict__ src_sorted,
    const float4* __restrict__ as4, const float4* __restrict__ ad4,
    f16* __restrict__ wE, float* __restrict__ den, int N, int E) {
  const int lane = threadIdx.x & 63;
  const int n = (blockIdx.x * 256 + threadIdx.x) >> 6;
  if (n >= N) return;
  const float4 adn = ad4[n];
  float4 d4 = make_float4(0.f, 0.f, 0.f, 0.f);
  const int beg = row_ptr[n], end = row_ptr[n + 1];
  for (int base = beg; base < end; base += 64) {
    int e = base + lane;
    if (e < end) {
      int idx = src_sorted[e];
      float4 a4 = as4[idx];
      f16 w0 = (f16)__expf(lrelu(a4.x + adn.x));
      f16 w1 = (f16)__expf(lrelu(a4.y + adn.y));
      f16 w2 = (f16)__expf(lrelu(a4.z + adn.z));
      f16 w3 = (f16)__expf(lrelu(a4.w + adn.w));
      wE[0 * (size_t)E + e] = w0;
      wE[1 * (size_t)E + e] = w1;
      wE[2 * (size_t)E + e] = w2;
      wE[3 * (size_t)E + e] = w3;
      d4.x += (float)w0; d4.y += (float)w1; d4.z += (float)w2; d4.w += (float)w3;
    }
  }
#pragma unroll
  for (int m = 1; m < 64; m <<= 1) {
    d4.x += __shfl_xor(d4.x, m, 64);
    d4.y += __shfl_xor(d4.y, m, 64);
    d4.z += __shfl_xor(d4.z, m, 64);
    d4.w += __shfl_xor(d4.w, m, 64);
  }
  if (lane == 0) {
    const float4 asn = as4[n];
    den[n * 4 + 0] = d4.x + (float)(f16)__expf(lrelu(asn.x + adn.x));
    den[n * 4 + 1] = d4.y + (float)(f16)__expf(lrelu(asn.y + adn.y));
    den[n * 4 + 2] = d4.z + (float)(f16)__expf(lrelu(asn.z + adn.z));
    den[n * 4 + 3] = d4.w + (float)(f16)__expf(lrelu(asn.w + adn.w));
  }
}

// ---- sliced GAT aggregation: slice = bid&7 -> one XCD -> L2-resident 4.4MB slice ----
// Wave = 1 node (x4 sequentially); lanes = 5 edges x 11 half2-channels (55 active).
__global__ __launch_bounds__(256) void gat_slice_kernel(
    const int* __restrict__ row_ptr, const int* __restrict__ src_sorted,
    const f16* __restrict__ hs,      // [8][N][22]
    const f16* __restrict__ wE,      // [4][E]
    const float* __restrict__ den,   // [N][4]
    const float* __restrict__ as4f, const float* __restrict__ ad4f,  // [N*4]
    const float* __restrict__ bias, f16* __restrict__ actv, int N, int E) {
  const int slice = blockIdx.x & 7;
  const int h = slice >> 1;
  const int wv = threadIdx.x >> 6;
  const int lane = threadIdx.x & 63;
  const int esub = lane / 11;          // 0..5
  const int c = lane - esub * 11;      // 0..10
  const bool act = (esub < 5);         // lanes 0..54
  const f16* hsS = hs + (size_t)slice * N * SLW;
  const f16* wEh = wE + (size_t)h * E;
  const int n0 = (blockIdx.x >> 3) * 16 + wv * 4;
  for (int k = 0; k < 4; ++k) {
    const int n = n0 + k;
    if (n >= N) break;                 // uniform per wave
    float ax = 0.f, ay = 0.f;
    // self loop (lanes esub==0 carry it)
    const float wself = (float)(f16)__expf(lrelu(as4f[n * 4 + h] + ad4f[n * 4 + h]));
    if (esub == 0) {
      __half2 u = *(const __half2*)(hsS + (size_t)n * SLW + 2 * c);
      float2 f = __half22float2(u);
      ax += f.x * wself; ay += f.y * wself;
    }
    const int beg = row_ptr[n];
    const int M = row_ptr[n + 1] - beg;
    for (int it = 0; it * 5 < M; ++it) {
      const int j = it * 5 + esub;
      if (act && j < M) {
        const int e = beg + j;
        const int idx = src_sorted[e];
        const float w = (float)wEh[e];
        __half2 u = *(const __half2*)(hsS + (size_t)idx * SLW + 2 * c);
        float2 f = __half22float2(u);
        ax += f.x * w; ay += f.y * w;
      }
    }
    // sum the 5 esub groups: lanes 0..10 pull from +11,+22,+33,+44
    float sx = ax + __shfl(ax, lane + 11, 64) + __shfl(ax, lane + 22, 64)
                  + __shfl(ax, lane + 33, 64) + __shfl(ax, lane + 44, 64);
    float sy = ay + __shfl(ay, lane + 11, 64) + __shfl(ay, lane + 22, 64)
                  + __shfl(ay, lane + 33, 64) + __shfl(ay, lane + 44, 64);
    if (lane < 11) {
      const float rden = 1.f / den[n * 4 + h];
      const int rc0 = (slice & 1) * SLW + 2 * lane;   // real channel within head
      const int rc1 = rc0 + 1;
      f16 o[2];
      o[0] = (rc0 < CC) ? (f16)eluf(sx * rden + bias[h * CC + rc0]) : (f16)0.f;
      o[1] = (rc1 < CC) ? (f16)eluf(sy * rden + bias[h * CC + rc1]) : (f16)0.f;
      *(uint*)(actv + (size_t)n * AP + slice * SLW + 2 * lane) = *(uint*)o;
    }
  }
}

// ---------------- counting sort by dst (XCD-locality passes) ----------------
__global__ void hist_kernel(const int* __restrict__ dst, int* __restrict__ cnt,
                            int E, int N) {
  int pass = blockIdx.x & (NPASS - 1);
  int e = (blockIdx.x >> 3) * 256 + threadIdx.x;
  if (e >= E) return;
  int d = dst[e];
  int lo = (int)((int64_t)pass * N / NPASS);
  int hi = (int)((int64_t)(pass + 1) * N / NPASS);
  if (d >= lo && d < hi) atomicAdd(&cnt[d], 1);
}

__global__ __launch_bounds__(256) void scan1_kernel(
    const int* __restrict__ cnt, int* __restrict__ rp1, int* __restrict__ blksum, int N) {
  __shared__ int lds[256];
  int t = threadIdx.x;
  int base = blockIdx.x * 1024 + t * 4;
  int v0 = (base + 0 < N) ? cnt[base + 0] : 0;
  int v1 = (base + 1 < N) ? cnt[base + 1] : 0;
  int v2 = (base + 2 < N) ? cnt[base + 2] : 0;
  int v3 = (base + 3 < N) ? cnt[base + 3] : 0;
  v1 += v0; v2 += v1; v3 += v2;
  lds[t] = v3;
  __syncthreads();
  for (int off = 1; off < 256; off <<= 1) {
    int add = (t >= off) ? lds[t - off] : 0;
    __syncthreads();
    lds[t] += add;
    __syncthreads();
  }
  int excl = lds[t] - v3;
  if (base + 0 < N) rp1[base + 0] = excl + v0;
  if (base + 1 < N) rp1[base + 1] = excl + v1;
  if (base + 2 < N) rp1[base + 2] = excl + v2;
  if (base + 3 < N) rp1[base + 3] = excl + v3;
  if (t == 255) blksum[blockIdx.x] = lds[255];
}

__global__ __launch_bounds__(256) void scan2_kernel(int* __restrict__ blksum, int nblk) {
  __shared__ int lds[256];
  int t = threadIdx.x;
  int v = (t < nblk) ? blksum[t] : 0;
  lds[t] = v;
  __syncthreads();
  for (int off = 1; off < 256; off <<= 1) {
    int add = (t >= off) ? lds[t - off] : 0;
    __syncthreads();
    lds[t] += add;
    __syncthreads();
  }
  if (t < nblk) blksum[t] = lds[t] - v;   // exclusive
}

__global__ void scan3_kernel(const int* __restrict__ blksum, int* __restrict__ rp1,
                             int* __restrict__ row_ptr0, int* __restrict__ cnt_cursor, int N) {
  int i = blockIdx.x * 256 + threadIdx.x;
  if (i >= N) return;
  int incl = rp1[i] + blksum[i >> 10];
  rp1[i] = incl;                         // row_ptr[i+1]
  cnt_cursor[i] = incl - cnt_cursor[i];  // row_ptr[i] (exclusive)
  if (i == 0) row_ptr0[0] = 0;
}

__global__ void scatter_gbound_kernel(
    const int* __restrict__ src, const int* __restrict__ dst,
    int* __restrict__ cursor, int* __restrict__ src_sorted,
    const int* __restrict__ batch, int* __restrict__ gstart,
    int E, int N, int G) {
  int pass = blockIdx.x & (NPASS - 1);
  int i = (blockIdx.x >> 3) * 256 + threadIdx.x;
  if (pass == 0 && i <= N) {
    if (i == 0) {
      for (int g = 0; g <= batch[0]; ++g) gstart[g] = 0;
    } else if (i == N) {
      for (int g = batch[N - 1] + 1; g <= G; ++g) gstart[g] = N;
    } else {
      int a = batch[i - 1], b = batch[i];
      for (int g = a + 1; g <= b; ++g) gstart[g] = i;
    }
  }
  if (i < E) {
    int d = dst[i];
    int lo = (int)((int64_t)pass * N / NPASS);
    int hi = (int)((int64_t)(pass + 1) * N / NPASS);
    if (d >= lo && d < hi) {
      int pos = atomicAdd(&cursor[d], 1);
      src_sorted[pos] = src[i];
    }
  }
}

// ---------------- mean pool ----------------
#define PSPLIT 16
__global__ __launch_bounds__(192) void pool2_kernel(
    const f16* __restrict__ x, const int* __restrict__ gstart,
    float* __restrict__ sums, int G) {
  int g = blockIdx.x;
  int t = threadIdx.x;
  if (t >= HC) return;
  int pos = (t / CC) * PH + t % CC;
  int beg = gstart[g], end = gstart[g + 1];
  float s = 0.f;
  for (int n = beg + (int)blockIdx.y; n < end; n += PSPLIT)
    s += (float)x[(int64_t)n * AP + pos];
  atomicAdd(sums + g * HC + t, s);
}

__global__ void out2_kernel(const float* __restrict__ sums, const int* __restrict__ gstart,
                            float* __restrict__ out, int G) {
  int i = blockIdx.x * 256 + threadIdx.x;
  if (i >= G * HC) return;
  int g = i / HC;
  float cnt = (float)(gstart[g + 1] - gstart[g]);
  out[i] = sums[i] / fmaxf(cnt, 1.f);
}

static inline int cdiv(int64_t a, int b) { return (int)((a + b - 1) / b); }

extern "C" void kernel_launch(void* const* d_in, const int* in_sizes, int n_in,
                              void* d_out, int out_size, void* d_ws, size_t ws_size,
                              hipStream_t stream) {
  const float* x      = (const float*)d_in[0];
  const int*   eidx   = (const int*)d_in[1];
  const int*   batch  = (const int*)d_in[2];
  const float* lin0_w = (const float*)d_in[3];
  const float* lin0_b = (const float*)d_in[4];
  const float* W[3]  = {(const float*)d_in[5],  (const float*)d_in[9],  (const float*)d_in[13]};
  const float* As[3] = {(const float*)d_in[6],  (const float*)d_in[10], (const float*)d_in[14]};
  const float* Ad[3] = {(const float*)d_in[7],  (const float*)d_in[11], (const float*)d_in[15]};
  const float* Bi[3] = {(const float*)d_in[8],  (const float*)d_in[12], (const float*)d_in[16]};

  const int N = in_sizes[2];
  const int E = in_sizes[1] / 2;
  const int G = out_size / HC;
  const int* src = eidx;
  const int* dst = eidx + E;

  // ---- workspace layout ----
  char* p = (char*)d_ws;
  f16* act0 = (f16*)p;  p += (size_t)N * A0P * 2;
  f16* actv = (f16*)p;  p += (size_t)N * AP * 2;
  f16* hs   = (f16*)p;  p += (size_t)8 * N * SLW * 2;   // sliced gather table
  f16* wE   = (f16*)p;  p += (size_t)4 * E * 2;         // per-layer edge weights
  f16* Wf0  = (f16*)p;  p += (size_t)4 * 2 * 64 * 8 * 2;
  f16* Wf1  = (f16*)p;  p += (size_t)11 * 2 * 64 * 8 * 2;
  f16* Wf2  = (f16*)p;  p += (size_t)11 * 6 * 64 * 8 * 2;
  f16* Wf3  = (f16*)p;  p += (size_t)11 * 6 * 64 * 8 * 2;
  float* aPad = (float*)p; p += (size_t)3 * 2 * 176 * 4;
  float* as_  = (float*)p; p += (size_t)N * NH * 4;
  float* ad_  = (float*)p; p += (size_t)N * NH * 4;
  float* den  = (float*)p; p += (size_t)N * NH * 4;
  float* sums = (float*)p; p += (size_t)G * HC * 4;
  int* gstart     = (int*)p; p += (size_t)(G + 1) * 4;
  int* row_ptr    = (int*)p; p += (size_t)(N + 1) * 4;
  int* cursor     = (int*)p; p += (size_t)N * 4;
  int* blksum     = (int*)p; p += 256 * 4;
  int* src_sorted = (int*)p; p += (size_t)E * 4;
  (void)ws_size;

  const int nblk = cdiv(N, 1024);
  const int mfma_blocks = cdiv(cdiv(N, 16), 4);
  const int agg_blocks = cdiv(N, 16) * 8;

  // ---- prep ----
  {
    int tot = N + G * HC + N * 4 + 3 * 2 * 176 + 4 * 2 * 64 + 11 * 2 * 64 + 2 * (11 * 6 * 64);
    prep_kernel<<<cdiv(tot, 256), 256, 0, stream>>>(
        lin0_w, W[0], W[1], W[2], As[0], Ad[0], As[1], Ad[1], As[2], Ad[2],
        Wf0, Wf1, Wf2, Wf3, aPad, cursor, sums, actv, N, G);
  }

  // ---- lin0 + elu ----
  mfma_gemm0_kernel<<<mfma_blocks, 256, 0, stream>>>(x, Wf0, lin0_b, act0, N);

  // ---- build dst-sorted CSR + graph boundaries ----
  hist_kernel<<<cdiv(E, 256) * NPASS, 256, 0, stream>>>(dst, cursor, E, N);
  scan1_kernel<<<nblk, 256, 0, stream>>>(cursor, row_ptr + 1, blksum, N);
  scan2_kernel<<<1, 256, 0, stream>>>(blksum, nblk);
  scan3_kernel<<<cdiv(N, 256), 256, 0, stream>>>(blksum, row_ptr + 1, row_ptr, cursor, N);
  {
    int nx = cdiv(E > N + 1 ? E : N + 1, 256) * NPASS;
    scatter_gbound_kernel<<<nx, 256, 0, stream>>>(
        src, dst, cursor, src_sorted, batch, gstart, E, N, G);
  }

  // ---- 3 GAT layers ----
  for (int l = 0; l < 3; ++l) {
    const float* asP = aPad + l * 352;
    const float* adP = aPad + l * 352 + 176;
    if (l == 0)
      mfma_gemmL_kernel<2><<<mfma_blocks, 256, 0, stream>>>(
          act0, Wf1, asP, adP, hs, (float4*)as_, (float4*)ad_, N);
    else
      mfma_gemmL_kernel<6><<<mfma_blocks, 256, 0, stream>>>(
          actv, (l == 1) ? Wf2 : Wf3, asP, adP, hs, (float4*)as_, (float4*)ad_, N);
    wden_kernel<<<cdiv(N, 4), 256, 0, stream>>>(
        row_ptr, src_sorted, (const float4*)as_, (const float4*)ad_, wE, den, N, E);
    gat_slice_kernel<<<agg_blocks, 256, 0, stream>>>(
        row_ptr, src_sorted, hs, wE, den, as_, ad_, Bi[l], actv, N, E);
  }

  // ---- mean pool per graph ----
  pool2_kernel<<<dim3(G, PSPLIT), 192, 0, stream>>>(actv, gstart, sums, G);
  out2_kernel<<<cdiv(G * HC, 256), 256, 0, stream>>>(sums, gstart, (float*)d_out, G);
}

// Round 11
// 774.918 us; speedup vs baseline: 2.2146x; 2.2146x over previous
//
#include <hip/hip_runtime.h>
#include <hip/hip_fp16.h>
#include <cstdint>

#define HC 168    // H*C (logical)
#define CC 42     // C per head
#define NH 4      // heads
#define PH 44     // padded channels per head
#define HP 176    // padded halves per h16 row
#define HPB 352   // bytes per h16 row
#define AP 192    // actv row pitch (halves), zero-padded K for KCN=6
#define A0P 64    // act0 row pitch (halves), KCN=2
#define NEG 0.2f
#define NPASS 8   // XCD-locality passes for hist/scatter

typedef _Float16 f16;
typedef __attribute__((ext_vector_type(8))) _Float16 f16x8;
typedef __attribute__((ext_vector_type(4))) float f32x4;

__device__ __forceinline__ float lrelu(float v) { return fmaxf(v, NEG * v); }
__device__ __forceinline__ float eluf(float v)  { return v > 0.f ? v : __expf(v) - 1.f; }

__device__ __forceinline__ float sel4(float4 w, int h) {
  float r = w.x;
  r = (h == 1) ? w.y : r;
  r = (h == 2) ? w.z : r;
  r = (h == 3) ? w.w : r;
  return r;
}

// ---- wconv as device fn: one item = one f16x8 of the fragment table ----
__device__ __forceinline__ void wconv_item(
    const float* __restrict__ W, f16* __restrict__ Wf, int i,
    int KCN, int kpad, int Fink, int cpad, int Ncols, int wstride) {
  int lane = i & 63;
  int t = i >> 6;
  int kc = t % KCN;
  int ct = t / KCN;
  int cl = ct * 16 + (lane & 15);
  int corig; bool cok;
  if (cpad) { int h = cl / PH, c = cl % PH; cok = (c < CC && h < NH); corig = h * CC + c; }
  else      { cok = (cl < Ncols); corig = cl; }
  f16 vals[8];
#pragma unroll
  for (int j = 0; j < 8; ++j) {
    int kp = kc * 32 + (lane >> 4) * 8 + j;
    int korig; bool kok;
    if (kpad) { int h = kp / PH, c = kp % PH; kok = (c < CC && h < NH && kp < HP); korig = h * CC + c; }
    else      { kok = (kp < Fink); korig = kp; }
    vals[j] = (kok && cok) ? (f16)W[korig * wstride + corig] : (f16)0.f;
  }
  *(f16x8*)(Wf + (size_t)i * 8) = *(f16x8*)vals;
}

// ---- prep: all weight tables + padded alpha tables + zero cursor/sums ----
__global__ void prep_kernel(
    const float* __restrict__ lin0_w,
    const float* __restrict__ W1, const float* __restrict__ W2, const float* __restrict__ W3,
    const float* __restrict__ as1, const float* __restrict__ ad1,
    const float* __restrict__ as2, const float* __restrict__ ad2,
    const float* __restrict__ as3, const float* __restrict__ ad3,
    f16* __restrict__ Wf0, f16* __restrict__ Wf1, f16* __restrict__ Wf2, f16* __restrict__ Wf3,
    float* __restrict__ aPad,   // [3][2][176]
    int* __restrict__ cursor, float* __restrict__ sums,
    int N, int G) {
  const int W0N = 4 * 2 * 64, W1N = 11 * 2 * 64, W2N = 11 * 6 * 64;
  int i = blockIdx.x * 256 + threadIdx.x;
  if (i < N) { cursor[i] = 0; return; }
  i -= N;
  if (i < G * HC) { sums[i] = 0.f; return; }
  i -= G * HC;
  if (i < 3 * 2 * 176) {
    int l = i / 352, rem = i % 352, which = rem / 176, col = rem % 176;
    const float* tabs[6] = {as1, ad1, as2, ad2, as3, ad3};
    const float* tab = tabs[l * 2 + which];
    int h = col / PH, c = col % PH;
    aPad[i] = (c < CC) ? tab[h * CC + c] : 0.f;
    return;
  }
  i -= 3 * 2 * 176;
  if (i < W0N) { wconv_item(lin0_w, Wf0, i, 2, 0, CC, 0, CC, CC); return; }
  i -= W0N;
  if (i < W1N) { wconv_item(W1, Wf1, i, 2, 0, CC, 1, HC, HC); return; }
  i -= W1N;
  if (i < W2N) { wconv_item(W2, Wf2, i, 6, 1, HC, 1, HC, HC); return; }
  i -= W2N;
  if (i < W2N) { wconv_item(W3, Wf3, i, 6, 1, HC, 1, HC, HC); return; }
}

// ---- lin0 MFMA: act0[N,64] = elu(f16(x) @ Wf0 + b); reads fp32 x directly ----
__global__ __launch_bounds__(256) void mfma_gemm0_kernel(
    const float* __restrict__ X, const f16* __restrict__ Wf,
    const float* __restrict__ bias, f16* __restrict__ Out, int N) {
  const int lane = threadIdx.x & 63;
  const int wid = (blockIdx.x * 256 + threadIdx.x) >> 6;
  const int row0 = wid * 16;
  if (row0 >= N) return;
  const int r = lane & 15, g = lane >> 4;
  f16x8 a[2];
  const float* xp = X + (int64_t)(row0 + r) * CC;
#pragma unroll
  for (int kc = 0; kc < 2; ++kc) {
#pragma unroll
    for (int j = 0; j < 8; ++j) {
      int k = kc * 32 + g * 8 + j;
      a[kc][j] = (k < CC) ? (f16)xp[k] : (f16)0.f;
    }
  }
  f16* op = Out + (int64_t)row0 * A0P;
#pragma unroll
  for (int ct = 0; ct < 4; ++ct) {
    f32x4 acc = {0.f, 0.f, 0.f, 0.f};
#pragma unroll
    for (int kc = 0; kc < 2; ++kc) {
      f16x8 b = *(const f16x8*)(Wf + (((size_t)ct * 2 + kc) * 64 + lane) * 8);
      acc = __builtin_amdgcn_mfma_f32_16x16x32_f16(a[kc], b, acc, 0, 0, 0);
    }
    const int col = ct * 16 + r;
    float bv = (col < CC) ? bias[col] : 0.f;
#pragma unroll
    for (int v = 0; v < 4; ++v) {
      f16 o = (col < CC) ? (f16)eluf(acc[v] + bv) : (f16)0.f;
      op[(int64_t)(g * 4 + v) * A0P + col] = o;
    }
  }
}

// ---- layer MFMA + fused alpha ----
template<int KCN>
__global__ __launch_bounds__(256) void mfma_gemmL_kernel(
    const f16* __restrict__ A, const f16* __restrict__ Wf,
    const float* __restrict__ asP, const float* __restrict__ adP,
    f16* __restrict__ Out, float4* __restrict__ as4, float4* __restrict__ ad4,
    int N) {
  const int lane = threadIdx.x & 63;
  const int wid = (blockIdx.x * 256 + threadIdx.x) >> 6;
  const int row0 = wid * 16;
  if (row0 >= N) return;
  const int r = lane & 15, g = lane >> 4;
  f16x8 a[KCN];
  const f16* ap = A + (int64_t)(row0 + r) * (KCN * 32) + g * 8;
#pragma unroll
  for (int kc = 0; kc < KCN; ++kc) a[kc] = *(const f16x8*)(ap + kc * 32);
  f16* op = Out + (int64_t)row0 * HP;
  float psA[4][4], psD[4][4];
#pragma unroll
  for (int h = 0; h < 4; ++h)
#pragma unroll
    for (int v = 0; v < 4; ++v) { psA[h][v] = 0.f; psD[h][v] = 0.f; }

#pragma unroll
  for (int ct = 0; ct < 11; ++ct) {
    f32x4 acc = {0.f, 0.f, 0.f, 0.f};
#pragma unroll
    for (int kc = 0; kc < KCN; ++kc) {
      f16x8 b = *(const f16x8*)(Wf + (((size_t)ct * KCN + kc) * 64 + lane) * 8);
      acc = __builtin_amdgcn_mfma_f32_16x16x32_f16(a[kc], b, acc, 0, 0, 0);
    }
    const int col = ct * 16 + r;
    const float aS = asP[col], aD = adP[col];
    const int hlo = (ct * 16) / PH;
    const bool hi = (col >= (hlo + 1) * PH);
#pragma unroll
    for (int v = 0; v < 4; ++v) {
      f16 hq = (f16)acc[v];
      op[(int64_t)(g * 4 + v) * HP + col] = hq;
      float hf = (float)hq;
      float tA = hf * aS, tD = hf * aD;
      psA[hlo][v] += hi ? 0.f : tA;
      psD[hlo][v] += hi ? 0.f : tD;
      if (hlo < 3) {
        psA[hlo + 1][v] += hi ? tA : 0.f;
        psD[hlo + 1][v] += hi ? tD : 0.f;
      }
    }
  }
#pragma unroll
  for (int h = 0; h < 4; ++h)
#pragma unroll
    for (int v = 0; v < 4; ++v) {
      float aa = psA[h][v], dd = psD[h][v];
#pragma unroll
      for (int m = 1; m < 16; m <<= 1) {
        aa += __shfl_xor(aa, m, 64);
        dd += __shfl_xor(dd, m, 64);
      }
      psA[h][v] = aa; psD[h][v] = dd;
    }
  if (r < 4) {
    int row = row0 + g * 4 + r;
    as4[row] = make_float4(psA[0][r], psA[1][r], psA[2][r], psA[3][r]);
  } else if (r < 8) {
    int rr = r - 4;
    int row = row0 + g * 4 + rr;
    ad4[row] = make_float4(psD[0][rr], psD[1][rr], psD[2][rr], psD[3][rr]);
  }
}

// ---------------- counting sort by dst (XCD-locality passes) ----------------
__global__ void hist_kernel(const int* __restrict__ dst, int* __restrict__ cnt,
                            int E, int N) {
  int pass = blockIdx.x & (NPASS - 1);
  int e = (blockIdx.x >> 3) * 256 + threadIdx.x;
  if (e >= E) return;
  int d = dst[e];
  int lo = (int)((int64_t)pass * N / NPASS);
  int hi = (int)((int64_t)(pass + 1) * N / NPASS);
  if (d >= lo && d < hi) atomicAdd(&cnt[d], 1);
}

__global__ __launch_bounds__(256) void scan1_kernel(
    const int* __restrict__ cnt, int* __restrict__ rp1, int* __restrict__ blksum, int N) {
  __shared__ int lds[256];
  int t = threadIdx.x;
  int base = blockIdx.x * 1024 + t * 4;
  int v0 = (base + 0 < N) ? cnt[base + 0] : 0;
  int v1 = (base + 1 < N) ? cnt[base + 1] : 0;
  int v2 = (base + 2 < N) ? cnt[base + 2] : 0;
  int v3 = (base + 3 < N) ? cnt[base + 3] : 0;
  v1 += v0; v2 += v1; v3 += v2;
  lds[t] = v3;
  __syncthreads();
  for (int off = 1; off < 256; off <<= 1) {
    int add = (t >= off) ? lds[t - off] : 0;
    __syncthreads();
    lds[t] += add;
    __syncthreads();
  }
  int excl = lds[t] - v3;
  if (base + 0 < N) rp1[base + 0] = excl + v0;
  if (base + 1 < N) rp1[base + 1] = excl + v1;
  if (base + 2 < N) rp1[base + 2] = excl + v2;
  if (base + 3 < N) rp1[base + 3] = excl + v3;
  if (t == 255) blksum[blockIdx.x] = lds[255];
}

__global__ __launch_bounds__(256) void scan2_kernel(int* __restrict__ blksum, int nblk) {
  __shared__ int lds[256];
  int t = threadIdx.x;
  int v = (t < nblk) ? blksum[t] : 0;
  lds[t] = v;
  __syncthreads();
  for (int off = 1; off < 256; off <<= 1) {
    int add = (t >= off) ? lds[t - off] : 0;
    __syncthreads();
    lds[t] += add;
    __syncthreads();
  }
  if (t < nblk) blksum[t] = lds[t] - v;   // exclusive
}

__global__ void scan3_kernel(const int* __restrict__ blksum, int* __restrict__ rp1,
                             int* __restrict__ row_ptr0, int* __restrict__ cnt_cursor, int N) {
  int i = blockIdx.x * 256 + threadIdx.x;
  if (i >= N) return;
  int incl = rp1[i] + blksum[i >> 10];
  rp1[i] = incl;                         // row_ptr[i+1]
  cnt_cursor[i] = incl - cnt_cursor[i];  // row_ptr[i] (exclusive)
  if (i == 0) row_ptr0[0] = 0;
}

// ---- scatter (XCD-locality passes) + graph boundaries ----
__global__ void scatter_gbound_kernel(
    const int* __restrict__ src, const int* __restrict__ dst,
    int* __restrict__ cursor, int* __restrict__ src_sorted,
    const int* __restrict__ batch, int* __restrict__ gstart,
    int E, int N, int G) {
  int pass = blockIdx.x & (NPASS - 1);
  int i = (blockIdx.x >> 3) * 256 + threadIdx.x;
  if (pass == 0 && i <= N) {
    if (i == 0) {
      for (int g = 0; g <= batch[0]; ++g) gstart[g] = 0;
    } else if (i == N) {
      for (int g = batch[N - 1] + 1; g <= G; ++g) gstart[g] = N;
    } else {
      int a = batch[i - 1], b = batch[i];
      for (int g = a + 1; g <= b; ++g) gstart[g] = i;
    }
  }
  if (i < E) {
    int d = dst[i];
    int lo = (int)((int64_t)pass * N / NPASS);
    int hi = (int)((int64_t)(pass + 1) * N / NPASS);
    if (d >= lo && d < hi) {
      int pos = atomicAdd(&cursor[d], 1);
      src_sorted[pos] = src[i];
    }
  }
}

// ---------------- fused GAT aggregation (r9-proven structure) ----------------
__global__ __launch_bounds__(256) void gat_agg_kernel(
    const int* __restrict__ row_ptr, const int* __restrict__ src_sorted,
    const f16* __restrict__ H16, const float4* __restrict__ as4,
    const float4* __restrict__ ad4_, const float* __restrict__ bias,
    f16* __restrict__ out, int N) {
  __shared__ int   loff[4][64];
  __shared__ float lw4[4][64][4];
  const int wv = threadIdx.x >> 6;
  const int lane = threadIdx.x & 63;
  const int wid = (blockIdx.x * 256 + threadIdx.x) >> 6;
  if (wid >= N) return;
  const int n = wid;
  const bool act = (lane < 44);
  const int hL = act ? (lane / 11) : 0;
  const int myoff = lane * 8;
  const float4 adn = ad4_[n];
  float ax = 0.f, ay = 0.f, az = 0.f, aw = 0.f, den = 0.f;

#define GAT_ACC(boff_, w_)                                                  \
  {                                                                         \
    den += w_;                                                              \
    if (act) {                                                              \
      float2 raw = *(const float2*)((const char*)H16 + (boff_) + myoff);    \
      __half2 u0 = *(__half2*)&raw.x, u1 = *(__half2*)&raw.y;               \
      float2 f0 = __half22float2(u0), f1 = __half22float2(u1);              \
      ax += f0.x * w_; ay += f0.y * w_;                                     \
      az += f1.x * w_; aw += f1.y * w_;                                     \
    }                                                                       \
  }

  // self loop
  {
    const float4 a4 = as4[n];
    float4 w4 = make_float4(__expf(lrelu(a4.x + adn.x)), __expf(lrelu(a4.y + adn.y)),
                            __expf(lrelu(a4.z + adn.z)), __expf(lrelu(a4.w + adn.w)));
    float w = sel4(w4, hL);
    GAT_ACC((int64_t)n * HPB, w);
  }

  const int beg = row_ptr[n], end = row_ptr[n + 1];
  for (int base = beg; base < end; base += 64) {
    const int m = min(64, end - base);
    int idx = (lane < m) ? src_sorted[base + lane] : n;
    float4 a4 = as4[idx];
    float4 w4 = make_float4(__expf(lrelu(a4.x + adn.x)), __expf(lrelu(a4.y + adn.y)),
                            __expf(lrelu(a4.z + adn.z)), __expf(lrelu(a4.w + adn.w)));
    loff[wv][lane] = idx * HPB;
    *(float4*)&lw4[wv][lane][0] = w4;

#define GAT_EDGE(jj)                                                        \
    {                                                                       \
      int boff = loff[wv][jj];                                              \
      float w = lw4[wv][jj][hL];                                            \
      GAT_ACC((int64_t)boff, w);                                            \
    }

    int j = 0;
    for (; j + 8 <= m; j += 8) {
      GAT_EDGE(j)     GAT_EDGE(j + 1) GAT_EDGE(j + 2) GAT_EDGE(j + 3)
      GAT_EDGE(j + 4) GAT_EDGE(j + 5) GAT_EDGE(j + 6) GAT_EDGE(j + 7)
    }
    for (; j < m; ++j) GAT_EDGE(j)
#undef GAT_EDGE
  }
#undef GAT_ACC

  if (lane < 48) {
    f16 o[4] = {(f16)0.f, (f16)0.f, (f16)0.f, (f16)0.f};
    if (act) {
      const int q = lane - hL * 11;
      const float acc[4] = {ax, ay, az, aw};
      const float rden = 1.f / den;
#pragma unroll
      for (int t = 0; t < 4; ++t) {
        int c = q * 4 + t;
        if (c < CC) o[t] = (f16)eluf(acc[t] * rden + bias[hL * CC + c]);
      }
    }
    *(uint2*)(out + (int64_t)n * AP + lane * 4) = *(uint2*)o;
  }
}

// ---------------- mean pool ----------------
#define PSPLIT 16
__global__ __launch_bounds__(192) void pool2_kernel(
    const f16* __restrict__ x, const int* __restrict__ gstart,
    float* __restrict__ sums, int G) {
  int g = blockIdx.x;
  int t = threadIdx.x;
  if (t >= HC) return;
  int pos = (t / CC) * PH + t % CC;
  int beg = gstart[g], end = gstart[g + 1];
  float s = 0.f;
  for (int n = beg + (int)blockIdx.y; n < end; n += PSPLIT)
    s += (float)x[(int64_t)n * AP + pos];
  atomicAdd(sums + g * HC + t, s);
}

__global__ void out2_kernel(const float* __restrict__ sums, const int* __restrict__ gstart,
                            float* __restrict__ out, int G) {
  int i = blockIdx.x * 256 + threadIdx.x;
  if (i >= G * HC) return;
  int g = i / HC;
  float cnt = (float)(gstart[g + 1] - gstart[g]);
  out[i] = sums[i] / fmaxf(cnt, 1.f);
}

static inline int cdiv(int64_t a, int b) { return (int)((a + b - 1) / b); }

extern "C" void kernel_launch(void* const* d_in, const int* in_sizes, int n_in,
                              void* d_out, int out_size, void* d_ws, size_t ws_size,
                              hipStream_t stream) {
  const float* x      = (const float*)d_in[0];
  const int*   eidx   = (const int*)d_in[1];
  const int*   batch  = (const int*)d_in[2];
  const float* lin0_w = (const float*)d_in[3];
  const float* lin0_b = (const float*)d_in[4];
  const float* W[3]  = {(const float*)d_in[5],  (const float*)d_in[9],  (const float*)d_in[13]};
  const float* As[3] = {(const float*)d_in[6],  (const float*)d_in[10], (const float*)d_in[14]};
  const float* Ad[3] = {(const float*)d_in[7],  (const float*)d_in[11], (const float*)d_in[15]};
  const float* Bi[3] = {(const float*)d_in[8],  (const float*)d_in[12], (const float*)d_in[16]};

  const int N = in_sizes[2];
  const int E = in_sizes[1] / 2;
  const int G = out_size / HC;
  const int* src = eidx;
  const int* dst = eidx + E;

  // ---- workspace layout ----
  char* p = (char*)d_ws;
  f16* act0 = (f16*)p;  p += (size_t)N * A0P * 2;
  f16* actv = (f16*)p;  p += (size_t)N * AP * 2;
  f16* h16  = (f16*)p;  p += (size_t)N * HP * 2;
  f16* Wf0  = (f16*)p;  p += (size_t)4 * 2 * 64 * 8 * 2;
  f16* Wf1  = (f16*)p;  p += (size_t)11 * 2 * 64 * 8 * 2;
  f16* Wf2  = (f16*)p;  p += (size_t)11 * 6 * 64 * 8 * 2;
  f16* Wf3  = (f16*)p;  p += (size_t)11 * 6 * 64 * 8 * 2;
  float* aPad = (float*)p; p += (size_t)3 * 2 * 176 * 4;
  float* as_  = (float*)p; p += (size_t)N * NH * 4;
  float* ad_  = (float*)p; p += (size_t)N * NH * 4;
  float* sums = (float*)p; p += (size_t)G * HC * 4;
  int* gstart     = (int*)p; p += (size_t)(G + 1) * 4;
  int* row_ptr    = (int*)p; p += (size_t)(N + 1) * 4;
  int* cursor     = (int*)p; p += (size_t)N * 4;
  int* blksum     = (int*)p; p += 256 * 4;
  int* src_sorted = (int*)p; p += (size_t)E * 4;
  (void)ws_size;

  const int nblk = cdiv(N, 1024);
  const int mfma_blocks = cdiv(cdiv(N, 16), 4);

  // ---- prep ----
  {
    int tot = N + G * HC + 3 * 2 * 176 + 4 * 2 * 64 + 11 * 2 * 64 + 2 * (11 * 6 * 64);
    prep_kernel<<<cdiv(tot, 256), 256, 0, stream>>>(
        lin0_w, W[0], W[1], W[2], As[0], Ad[0], As[1], Ad[1], As[2], Ad[2],
        Wf0, Wf1, Wf2, Wf3, aPad, cursor, sums, N, G);
  }

  // ---- lin0 + elu ----
  mfma_gemm0_kernel<<<mfma_blocks, 256, 0, stream>>>(x, Wf0, lin0_b, act0, N);

  // ---- build dst-sorted CSR + graph boundaries (XCD-pass hist/scatter) ----
  hist_kernel<<<cdiv(E, 256) * NPASS, 256, 0, stream>>>(dst, cursor, E, N);
  scan1_kernel<<<nblk, 256, 0, stream>>>(cursor, row_ptr + 1, blksum, N);
  scan2_kernel<<<1, 256, 0, stream>>>(blksum, nblk);
  scan3_kernel<<<cdiv(N, 256), 256, 0, stream>>>(blksum, row_ptr + 1, row_ptr, cursor, N);
  {
    int nx = cdiv(E > N + 1 ? E : N + 1, 256) * NPASS;
    scatter_gbound_kernel<<<nx, 256, 0, stream>>>(
        src, dst, cursor, src_sorted, batch, gstart, E, N, G);
  }

  // ---- 3 GAT layers ----
  for (int l = 0; l < 3; ++l) {
    const float* asP = aPad + l * 352;
    const float* adP = aPad + l * 352 + 176;
    if (l == 0)
      mfma_gemmL_kernel<2><<<mfma_blocks, 256, 0, stream>>>(
          act0, Wf1, asP, adP, h16, (float4*)as_, (float4*)ad_, N);
    else
      mfma_gemmL_kernel<6><<<mfma_blocks, 256, 0, stream>>>(
          actv, (l == 1) ? Wf2 : Wf3, asP, adP, h16, (float4*)as_, (float4*)ad_, N);
    gat_agg_kernel<<<cdiv(N, 4), 256, 0, stream>>>(
        row_ptr, src_sorted, h16, (const float4*)as_, (const float4*)ad_, Bi[l], actv, N);
  }

  // ---- mean pool per graph ----
  pool2_kernel<<<dim3(G, PSPLIT), 192, 0, stream>>>(actv, gstart, sums, G);
  out2_kernel<<<cdiv(G * HC, 256), 256, 0, stream>>>(sums, gstart, (float*)d_out, G);
}